// Round 5
// baseline (161.996 us; speedup 1.0000x reference)
//
#include <hip/hip_runtime.h>
#include <hip/hip_bf16.h>
#include <math.h>

// Transformer-XL relative multi-head attention, bf16 MFMA implementation.
// B=4, S=1024, H=16, Dh=32, DIM=512.
//
// relative_shift identity: shifted[q,k] = qv[q]·pA[m] + qv[q+1]·pB[m],
// m = k - q + S - 1;  pA[m]=Z[S+1+m], pB[m]=Z[m] with a single zero-padded
// tensor Z (rows [S+1, 2S+1) = p, all else 0).
//
// Round 5: fixes R4's workspace overlap (plsum sat on top of Wo inside wb ->
// NaN). plsum moved to its own region at +52 MB. Structure otherwise
// identical to R4: 4-wave blocks, 2-way split-S, 32 waves/CU, max-free
// softmax, merged phZ, scale folded into q projections.

typedef float f32x4 __attribute__((ext_vector_type(4)));
typedef __bf16 bf16x8 __attribute__((ext_vector_type(8)));

#define MFMA16(a, b, c) __builtin_amdgcn_mfma_f32_16x16x32_bf16((a), (b), (c), 0, 0, 0)

constexpr int Bb  = 4;
constexpr int S   = 1024;
constexpr int H   = 16;
constexpr int Dh  = 32;
constexpr int DIM = 512;
constexpr float SCALE = 0.17677669529663687f;  // 1/sqrt(32)
constexpr int ZROWS = 3 * S + 16;              // phZ rows per (b,h)

constexpr size_t XN = (size_t)Bb * S * DIM;   // elems per activation tensor
constexpr size_t WN = (size_t)DIM * DIM;      // elems per weight matrix

__device__ inline bf16x8 cvt8(const float* __restrict__ p) {
  f32x4 a = *(const f32x4*)p;
  f32x4 b = *(const f32x4*)(p + 4);
  bf16x8 r;
  r[0] = (__bf16)a[0]; r[1] = (__bf16)a[1]; r[2] = (__bf16)a[2]; r[3] = (__bf16)a[3];
  r[4] = (__bf16)b[0]; r[5] = (__bf16)b[1]; r[6] = (__bf16)b[2]; r[7] = (__bf16)b[3];
  return r;
}

__device__ inline void gload_lds16(const __bf16* g, __bf16* l) {
  __builtin_amdgcn_global_load_lds(
      (const __attribute__((address_space(1))) unsigned int*)g,
      (__attribute__((address_space(3))) unsigned int*)l, 16, 0, 0);
}

// ---------------------------------------------------------------------------
// Kernel 0: f32 -> bf16 conversion of activations (y=0..3) and weights (y=4..8).
// ---------------------------------------------------------------------------
__global__ __launch_bounds__(256) void conv_kernel(
    const float* __restrict__ q, const float* __restrict__ k,
    const float* __restrict__ v, const float* __restrict__ p,
    const float* __restrict__ wq, const float* __restrict__ wk,
    const float* __restrict__ wv, const float* __restrict__ wp,
    const float* __restrict__ wo,
    __bf16* __restrict__ xb, __bf16* __restrict__ wb)
{
  const int y = blockIdx.y;
  const float* src;
  size_t n;
  __bf16* dst;
  if (y < 4) {
    src = (y == 0) ? q : (y == 1) ? k : (y == 2) ? v : p;
    n = XN;
    dst = xb + (size_t)y * XN;
  } else {
    const int w = y - 4;
    src = (w == 0) ? wq : (w == 1) ? wk : (w == 2) ? wv : (w == 3) ? wp : wo;
    n = WN;
    dst = wb + (size_t)w * WN;
  }
  const size_t i = ((size_t)blockIdx.x * 256 + threadIdx.x) * 8;
  if (i >= n) return;
  *(bf16x8*)(dst + i) = cvt8(src + i);
}

// ---------------------------------------------------------------------------
// Kernel 1: tiled bf16 GEMM  C[M, N=512] = A @ B^T, K=512.
// 128x128 block tile, BK=64, 4 waves. global_load_lds(16B), XOR-swizzled
// source + read (linear LDS dest). XCD co-location of col-blocks.
// mode 0: z=0..3 projections; mode 1: z=4 outproj (f32 + bo).
// ---------------------------------------------------------------------------
__global__ __launch_bounds__(256) void gemm_kernel(
    const __bf16* __restrict__ xb, const __bf16* __restrict__ wb,
    const __bf16* __restrict__ ctxp,
    const float* __restrict__ bq, const float* __restrict__ bk,
    const float* __restrict__ bv, const float* __restrict__ bo,
    const float* __restrict__ ub, const float* __restrict__ vb,
    __bf16* __restrict__ qu, __bf16* __restrict__ qv,
    __bf16* __restrict__ kk, __bf16* __restrict__ vt,
    __bf16* __restrict__ phZ,
    float* __restrict__ outp, int mode)
{
  __shared__ __align__(16) __bf16 As[128 * 64];
  __shared__ __align__(16) __bf16 Bs[128 * 64];

  const int bid = blockIdx.x;
  const int u = bid >> 3;
  const int by = u & 3;
  const int idx = (bid & 7) + 8 * (u >> 2);
  int bx, z;
  if (mode == 0) { bx = idx & 31; z = idx >> 5; }
  else           { bx = idx;      z = 4; }

  const __bf16* Ag = (z < 4) ? (xb + (size_t)z * XN) : ctxp;
  const __bf16* Bg = wb + (size_t)z * WN;

  const int tid = threadIdx.x;
  const int wid = tid >> 6;
  const int ln = tid & 63;
  const int lm = ln & 15, lg = ln >> 4;
  const int wr = wid >> 1, wc = wid & 1;
  const int brow = bx * 128;
  const int bcol = by * 128;

  const int srow = ln >> 3;
  const int sc   = ln & 7;

  f32x4 acc[4][4] = {};

  for (int kt = 0; kt < DIM / 64; ++kt) {
    const int k0 = kt * 64;
#pragma unroll
    for (int i = 0; i < 4; ++i) {
      const int rb = wid * 32 + i * 8;
      const int r = rb + srow;
      const int cg = sc ^ (r & 7);
      gload_lds16(Ag + (size_t)(brow + r) * DIM + k0 + cg * 8, &As[rb * 64]);
      gload_lds16(Bg + (size_t)(bcol + r) * DIM + k0 + cg * 8, &Bs[rb * 64]);
    }
    __syncthreads();

#pragma unroll
    for (int ks = 0; ks < 2; ++ks) {
      bf16x8 a[4], b[4];
#pragma unroll
      for (int m = 0; m < 4; ++m) {
        const int row = wr * 64 + m * 16 + lm;
        const int cc = (ks * 4 + lg) ^ (row & 7);
        a[m] = *(const bf16x8*)&As[row * 64 + cc * 8];
      }
#pragma unroll
      for (int n = 0; n < 4; ++n) {
        const int row = wc * 64 + n * 16 + lm;
        const int cc = (ks * 4 + lg) ^ (row & 7);
        b[n] = *(const bf16x8*)&Bs[row * 64 + cc * 8];
      }
#pragma unroll
      for (int m = 0; m < 4; ++m)
#pragma unroll
        for (int n = 0; n < 4; ++n)
          acc[m][n] = MFMA16(a[m], b[n], acc[m][n]);
    }
    __syncthreads();
  }

  // ---- epilogue
#pragma unroll
  for (int n = 0; n < 4; ++n) {
    const int o = bcol + wc * 64 + n * 16 + lm;
    float bias = 0.f, ubv = 0.f, vbv = 0.f;
    if (z == 0) { bias = bq[o]; ubv = ub[o]; vbv = vb[o]; }
    else if (z == 1) bias = bk[o];
    else if (z == 2) bias = bv[o];
    else if (z == 4) bias = bo[o];
    const int h = o >> 5, d = o & 31;
#pragma unroll
    for (int m = 0; m < 4; ++m) {
#pragma unroll
      for (int r = 0; r < 4; ++r) {
        const int M = brow + wr * 64 + m * 16 + lg * 4 + r;
        const float val = acc[m][n][r];
        if (z == 4) {
          outp[(size_t)M * DIM + o] = val + bias;
          continue;
        }
        const int b = M >> 10, s = M & (S - 1);
        const int bh = b * H + h;
        if (z == 0) {
          // 1/sqrt(Dh) folded in here (scores use pre-scaled q).
          const size_t idx2 = ((size_t)bh * S + s) * Dh + d;
          qu[idx2] = (__bf16)((val + bias + ubv) * SCALE);
          qv[idx2] = (__bf16)((val + bias + vbv) * SCALE);
        } else if (z == 1) {
          kk[((size_t)bh * S + s) * Dh + d] = (__bf16)(val + bias);
        } else if (z == 2) {
          vt[((size_t)bh * Dh + d) * S + s] = (__bf16)(val + bias);
        } else {
          // phZ rows [S+1, 2S+1) = p; everything else pre-zeroed by memset.
          phZ[((size_t)bh * ZROWS + (S + 1 + s)) * Dh + d] = (__bf16)val;
        }
      }
    }
  }
}

// ---------------------------------------------------------------------------
// Kernel 2: fused attention, split-S. 256-thread blocks, 4 independent waves;
// wave = (16 q-rows) x (512 k). Grid 2048 -> 32 waves/CU. Max-free softmax;
// f32 partials (ct, sum) written for the combine kernel.
// ---------------------------------------------------------------------------
__global__ __launch_bounds__(256, 8) void attn_kernel(
    const __bf16* __restrict__ qu, const __bf16* __restrict__ qv,
    const __bf16* __restrict__ kk, const __bf16* __restrict__ vt,
    const __bf16* __restrict__ phZ,
    float* __restrict__ pctx, float* __restrict__ plsum)
{
  __shared__ float pos_all[4 * 16 * 49];
  __shared__ __align__(16) __bf16 at_all[4 * 16 * 40];

  const int tid = threadIdx.x;
  const int wid = tid >> 6;
  const int l = tid & 63;
  const int lm = l & 15, lg = l >> 4;

  float* pos_lds = pos_all + wid * 16 * 49;
  __bf16* at_lds = at_all + wid * 16 * 40;

  // bid -> (xcd-resident bh, q-group, k-half)
  const int bid = blockIdx.x;               // [0, 2048)
  const int j = bid >> 3;
  const int bh = (bid & 7) + 8 * (j & 7);
  const int rest = j >> 3;                  // [0, 32)
  const int qg = rest >> 1;                 // [0, 16)
  const int khalf = rest & 1;
  const int q0 = (qg * 4 + wid) * 16;

  const __bf16* qub = qu + (size_t)bh * S * Dh;
  const __bf16* qvb = qv + (size_t)bh * S * Dh;
  const __bf16* kb  = kk + (size_t)bh * S * Dh;
  const __bf16* vtb = vt + (size_t)bh * Dh * S;
  const __bf16* pZb = phZ + (size_t)bh * ZROWS * Dh;

  const bf16x8 au  = *(const bf16x8*)(qub + (size_t)(q0 + lm) * Dh + lg * 8);
  const bf16x8 avA = *(const bf16x8*)(qvb + (size_t)(q0 + lm) * Dh + lg * 8);
  // row q+1 for the pB term; the one-past read is multiplied by zero pB rows.
  const bf16x8 avB = *(const bf16x8*)(qvb + (size_t)(q0 + 1 + lm) * Dh + lg * 8);

  float lrun[4] = {0.f, 0.f, 0.f, 0.f};
  f32x4 cta = {0.f,0.f,0.f,0.f}, ctb = {0.f,0.f,0.f,0.f};
  const f32x4 zero4 = {0.f,0.f,0.f,0.f};

  const int kbeg = khalf * (S / 2);
  for (int k0 = kbeg; k0 < kbeg + S / 2; k0 += 32) {
    // ---- content scores (q pre-scaled): [16 q x 32 k]
    bf16x8 bk0 = *(const bf16x8*)(kb + (size_t)(k0 + lm) * Dh + lg * 8);
    bf16x8 bk1 = *(const bf16x8*)(kb + (size_t)(k0 + 16 + lm) * Dh + lg * 8);
    f32x4 c0 = MFMA16(au, bk0, zero4);
    f32x4 c1 = MFMA16(au, bk1, zero4);

    // ---- positional scores over the 47-wide m window
    const int mlo = k0 - q0 + (S - 16);
#pragma unroll
    for (int t = 0; t < 3; ++t) {
      const int mrow = mlo + t * 16 + lm;
      bf16x8 fa = *(const bf16x8*)(pZb + (size_t)(S + 1 + mrow) * Dh + lg * 8);
      bf16x8 fb = *(const bf16x8*)(pZb + (size_t)mrow * Dh + lg * 8);
      f32x4 pt = MFMA16(avB, fb, zero4);
      pt = MFMA16(avA, fa, pt);
#pragma unroll
      for (int r = 0; r < 4; ++r)
        pos_lds[(lg * 4 + r) * 49 + t * 16 + lm] = pt[r];
    }

    // ---- combine + exp (max-free: scores bounded, softmax shift-invariant)
#pragma unroll
    for (int r = 0; r < 4; ++r) {
      const int qr = lg * 4 + r;
      const float s0 = c0[r] + pos_lds[qr * 49 + (lm - qr + 15)];
      const float s1 = c1[r] + pos_lds[qr * 49 + (lm - qr + 31)];
      const float p0 = __expf(s0);
      const float p1 = __expf(s1);
      lrun[r] += p0 + p1;
      at_lds[qr * 40 + lm] = (__bf16)p0;
      at_lds[qr * 40 + 16 + lm] = (__bf16)p1;
    }

    // ---- attn @ V
    bf16x8 af  = *(const bf16x8*)(at_lds + lm * 40 + lg * 8);
    bf16x8 bv0 = *(const bf16x8*)(vtb + (size_t)lm * S + k0 + lg * 8);
    bf16x8 bv1 = *(const bf16x8*)(vtb + (size_t)(lm + 16) * S + k0 + lg * 8);
    cta = MFMA16(af, bv0, cta);
    ctb = MFMA16(af, bv1, ctb);
  }

  // ---- reduce row sums across 16-lane group; store f32 partials
#pragma unroll
  for (int r = 0; r < 4; ++r) {
    float rs = lrun[r];
    rs += __shfl_xor(rs, 1);
    rs += __shfl_xor(rs, 2);
    rs += __shfl_xor(rs, 4);
    rs += __shfl_xor(rs, 8);
    lrun[r] = rs;
  }

  float* pc = pctx + (((size_t)khalf * 64 + bh) * S) * Dh;
#pragma unroll
  for (int r = 0; r < 4; ++r) {
    const int s = q0 + lg * 4 + r;
    pc[(size_t)s * Dh + lm] = cta[r];
    pc[(size_t)s * Dh + 16 + lm] = ctb[r];
    if (lm == 0) plsum[((size_t)khalf * 64 + bh) * S + s] = lrun[r];
  }
}

// ---------------------------------------------------------------------------
// Kernel 3: combine split-S partials -> ctx bf16 [B, S, DIM].
// ---------------------------------------------------------------------------
__global__ __launch_bounds__(256) void combine_kernel(
    const float* __restrict__ pctx, const float* __restrict__ plsum,
    __bf16* __restrict__ ctx)
{
  const size_t flat = (size_t)blockIdx.x * 256 + threadIdx.x;  // [0, 64*1024*4)
  const int d0 = (int)(flat & 3) * 8;
  const int s = (int)(flat >> 2) & (S - 1);
  const int bh = (int)(flat >> 12);
  const int b = bh >> 4, h = bh & (H - 1);

  const size_t base0 = (((size_t)bh) * S + s) * Dh + d0;
  const size_t base1 = (((size_t)64 + bh) * S + s) * Dh + d0;
  f32x4 a0 = *(const f32x4*)(pctx + base0);
  f32x4 a1 = *(const f32x4*)(pctx + base0 + 4);
  f32x4 b0 = *(const f32x4*)(pctx + base1);
  f32x4 b1 = *(const f32x4*)(pctx + base1 + 4);
  const float inv = 1.f / (plsum[(size_t)bh * S + s] + plsum[((size_t)64 + bh) * S + s]);

  bf16x8 r;
#pragma unroll
  for (int i = 0; i < 4; ++i) {
    r[i] = (__bf16)((a0[i] + b0[i]) * inv);
    r[4 + i] = (__bf16)((a1[i] + b1[i]) * inv);
  }
  *(bf16x8*)(ctx + ((size_t)b * S + s) * DIM + h * Dh + d0) = r;
}

// ---------------------------------------------------------------------------
extern "C" void kernel_launch(void* const* d_in, const int* in_sizes, int n_in,
                              void* d_out, int out_size, void* d_ws, size_t ws_size,
                              hipStream_t stream) {
  const float* query = (const float*)d_in[0];
  const float* key   = (const float*)d_in[1];
  const float* value = (const float*)d_in[2];
  const float* pos   = (const float*)d_in[3];
  const float* Wq = (const float*)d_in[4];
  const float* bq = (const float*)d_in[5];
  const float* Wk = (const float*)d_in[6];
  const float* bk = (const float*)d_in[7];
  const float* Wv = (const float*)d_in[8];
  const float* bv = (const float*)d_in[9];
  const float* Wp = (const float*)d_in[10];
  const float* ub = (const float*)d_in[11];
  const float* vb = (const float*)d_in[12];
  const float* Wo = (const float*)d_in[13];
  const float* bo = (const float*)d_in[14];
  float* out = (float*)d_out;

  char* ws = (char*)d_ws;
  const size_t MB = 1ull << 20;
  // Layout (no overlaps except the intentional, time-disjoint pctx/xb alias):
  //   [ 0,16) MB : xb (4x bf16 activations)  -- dead after gemm mode 0
  //   [ 0,16) MB : pctx [2,64,S,32] f32      -- written by attn (after xb dead)
  //   [16,18.5)  : wb (5x bf16 weights)      -- live until gemm mode 1
  //   [19,23)    : qu   [23,27): qv   [27,31): kk   [31,35): vt
  //   [35,47.7)  : phZ [B*H, 3S+16, 32]
  //   [48,52)    : ctx bf16
  //   [52,52.5)  : plsum [2,64,S] f32        -- its own region (R4 bug fix)
  __bf16* xb    = (__bf16*)(ws + 0 * MB);
  float*  pctx  = (float*)(ws + 0 * MB);
  __bf16* wb    = (__bf16*)(ws + 16 * MB);
  __bf16* qu    = (__bf16*)(ws + 19 * MB);
  __bf16* qv    = (__bf16*)(ws + 23 * MB);
  __bf16* kk    = (__bf16*)(ws + 27 * MB);
  __bf16* vt    = (__bf16*)(ws + 31 * MB);
  __bf16* phZ   = (__bf16*)(ws + 35 * MB);
  __bf16* ctx   = (__bf16*)(ws + 48 * MB);
  float*  plsum = (float*)(ws + 52 * MB);

  conv_kernel<<<dim3(1024, 9), dim3(256), 0, stream>>>(
      query, key, value, pos, Wq, Wk, Wv, Wp, Wo, xb, wb);

  hipMemsetAsync(phZ, 0, (size_t)64 * ZROWS * Dh * sizeof(__bf16), stream);

  gemm_kernel<<<dim3(512), dim3(256), 0, stream>>>(
      xb, wb, ctx, bq, bk, bv, bo, ub, vb,
      qu, qv, kk, vt, phZ, out, 0);

  attn_kernel<<<dim3(2048), dim3(256), 0, stream>>>(
      qu, qv, kk, vt, phZ, pctx, plsum);

  combine_kernel<<<dim3(1024), dim3(256), 0, stream>>>(pctx, plsum, ctx);

  gemm_kernel<<<dim3(128), dim3(256), 0, stream>>>(
      xb, wb, ctx, bq, bk, bv, bo, ub, vb,
      qu, qv, kk, vt, phZ, out, 1);
}

// Round 6
// 125.302 us; speedup vs baseline: 1.2928x; 1.2928x over previous
//
#include <hip/hip_runtime.h>
#include <hip/hip_bf16.h>
#include <math.h>

// Transformer-XL relative multi-head attention, bf16 MFMA implementation.
// B=4, S=1024, H=16, Dh=32, DIM=512.
//
// relative_shift identity: shifted[q,k] = qv[q]·pA[m] + qv[q+1]·pB[m],
// m = k - q + S - 1;  pA[m]=Z[S+1+m], pB[m]=Z[m] with a single zero-padded
// tensor Z (rows [S+1, 2S+1) = p, all else 0).
//
// Round 6: attn inner loop de-serialized. (1) pos diagonal gather via
// register __shfl (source lane (l&48)|((lm-qr+15)&15), loop-invariant) —
// replaces the conflicted pos_lds write/read roundtrip. (2) wave-uniform
// skip of all-zero pA/pB windows (only ~2 near-diagonal tiles need both).
// (3) V^T stored k-interleaved (0,16,1,17,...) so P stores are packed
// b32 writes. (4) split-S + partials + combine dropped (L2 thrash: FETCH
// was 3x working set); full-S per wave, at_lds double-buffered, unroll x2.

typedef float f32x4 __attribute__((ext_vector_type(4)));
typedef __bf16 bf16x8 __attribute__((ext_vector_type(8)));
typedef __bf16 bf16x2 __attribute__((ext_vector_type(2)));

#define MFMA16(a, b, c) __builtin_amdgcn_mfma_f32_16x16x32_bf16((a), (b), (c), 0, 0, 0)

constexpr int Bb  = 4;
constexpr int S   = 1024;
constexpr int H   = 16;
constexpr int Dh  = 32;
constexpr int DIM = 512;
constexpr float SCALE = 0.17677669529663687f;  // 1/sqrt(32)
constexpr int ZROWS = 3 * S + 16;              // phZ rows per (b,h)

constexpr size_t XN = (size_t)Bb * S * DIM;   // elems per activation tensor
constexpr size_t WN = (size_t)DIM * DIM;      // elems per weight matrix

__device__ inline bf16x8 cvt8(const float* __restrict__ p) {
  f32x4 a = *(const f32x4*)p;
  f32x4 b = *(const f32x4*)(p + 4);
  bf16x8 r;
  r[0] = (__bf16)a[0]; r[1] = (__bf16)a[1]; r[2] = (__bf16)a[2]; r[3] = (__bf16)a[3];
  r[4] = (__bf16)b[0]; r[5] = (__bf16)b[1]; r[6] = (__bf16)b[2]; r[7] = (__bf16)b[3];
  return r;
}

__device__ inline void gload_lds16(const __bf16* g, __bf16* l) {
  __builtin_amdgcn_global_load_lds(
      (const __attribute__((address_space(1))) unsigned int*)g,
      (__attribute__((address_space(3))) unsigned int*)l, 16, 0, 0);
}

// ---------------------------------------------------------------------------
// Kernel 0: f32 -> bf16 conversion of activations (y=0..3) and weights (y=4..8).
// ---------------------------------------------------------------------------
__global__ __launch_bounds__(256) void conv_kernel(
    const float* __restrict__ q, const float* __restrict__ k,
    const float* __restrict__ v, const float* __restrict__ p,
    const float* __restrict__ wq, const float* __restrict__ wk,
    const float* __restrict__ wv, const float* __restrict__ wp,
    const float* __restrict__ wo,
    __bf16* __restrict__ xb, __bf16* __restrict__ wb)
{
  const int y = blockIdx.y;
  const float* src;
  size_t n;
  __bf16* dst;
  if (y < 4) {
    src = (y == 0) ? q : (y == 1) ? k : (y == 2) ? v : p;
    n = XN;
    dst = xb + (size_t)y * XN;
  } else {
    const int w = y - 4;
    src = (w == 0) ? wq : (w == 1) ? wk : (w == 2) ? wv : (w == 3) ? wp : wo;
    n = WN;
    dst = wb + (size_t)w * WN;
  }
  const size_t i = ((size_t)blockIdx.x * 256 + threadIdx.x) * 8;
  if (i >= n) return;
  *(bf16x8*)(dst + i) = cvt8(src + i);
}

// ---------------------------------------------------------------------------
// Kernel 1: tiled bf16 GEMM  C[M, N=512] = A @ B^T, K=512.
// 128x128 block tile, BK=64, 4 waves. global_load_lds(16B), XOR-swizzled
// source + read (linear LDS dest). XCD co-location of col-blocks.
// mode 0: z=0..3 projections; mode 1: z=4 outproj (f32 + bo).
// ---------------------------------------------------------------------------
__global__ __launch_bounds__(256) void gemm_kernel(
    const __bf16* __restrict__ xb, const __bf16* __restrict__ wb,
    const __bf16* __restrict__ ctxp,
    const float* __restrict__ bq, const float* __restrict__ bk,
    const float* __restrict__ bv, const float* __restrict__ bo,
    const float* __restrict__ ub, const float* __restrict__ vb,
    __bf16* __restrict__ qu, __bf16* __restrict__ qv,
    __bf16* __restrict__ kk, __bf16* __restrict__ vt,
    __bf16* __restrict__ phZ,
    float* __restrict__ outp, int mode)
{
  __shared__ __align__(16) __bf16 As[128 * 64];
  __shared__ __align__(16) __bf16 Bs[128 * 64];

  const int bid = blockIdx.x;
  const int u = bid >> 3;
  const int by = u & 3;
  const int idx = (bid & 7) + 8 * (u >> 2);
  int bx, z;
  if (mode == 0) { bx = idx & 31; z = idx >> 5; }
  else           { bx = idx;      z = 4; }

  const __bf16* Ag = (z < 4) ? (xb + (size_t)z * XN) : ctxp;
  const __bf16* Bg = wb + (size_t)z * WN;

  const int tid = threadIdx.x;
  const int wid = tid >> 6;
  const int ln = tid & 63;
  const int lm = ln & 15, lg = ln >> 4;
  const int wr = wid >> 1, wc = wid & 1;
  const int brow = bx * 128;
  const int bcol = by * 128;

  const int srow = ln >> 3;
  const int sc   = ln & 7;

  f32x4 acc[4][4] = {};

  for (int kt = 0; kt < DIM / 64; ++kt) {
    const int k0 = kt * 64;
#pragma unroll
    for (int i = 0; i < 4; ++i) {
      const int rb = wid * 32 + i * 8;
      const int r = rb + srow;
      const int cg = sc ^ (r & 7);
      gload_lds16(Ag + (size_t)(brow + r) * DIM + k0 + cg * 8, &As[rb * 64]);
      gload_lds16(Bg + (size_t)(bcol + r) * DIM + k0 + cg * 8, &Bs[rb * 64]);
    }
    __syncthreads();

#pragma unroll
    for (int ks = 0; ks < 2; ++ks) {
      bf16x8 a[4], b[4];
#pragma unroll
      for (int m = 0; m < 4; ++m) {
        const int row = wr * 64 + m * 16 + lm;
        const int cc = (ks * 4 + lg) ^ (row & 7);
        a[m] = *(const bf16x8*)&As[row * 64 + cc * 8];
      }
#pragma unroll
      for (int n = 0; n < 4; ++n) {
        const int row = wc * 64 + n * 16 + lm;
        const int cc = (ks * 4 + lg) ^ (row & 7);
        b[n] = *(const bf16x8*)&Bs[row * 64 + cc * 8];
      }
#pragma unroll
      for (int m = 0; m < 4; ++m)
#pragma unroll
        for (int n = 0; n < 4; ++n)
          acc[m][n] = MFMA16(a[m], b[n], acc[m][n]);
    }
    __syncthreads();
  }

  // ---- epilogue
#pragma unroll
  for (int n = 0; n < 4; ++n) {
    const int o = bcol + wc * 64 + n * 16 + lm;
    float bias = 0.f, ubv = 0.f, vbv = 0.f;
    if (z == 0) { bias = bq[o]; ubv = ub[o]; vbv = vb[o]; }
    else if (z == 1) bias = bk[o];
    else if (z == 2) bias = bv[o];
    else if (z == 4) bias = bo[o];
    const int h = o >> 5, d = o & 31;
#pragma unroll
    for (int m = 0; m < 4; ++m) {
#pragma unroll
      for (int r = 0; r < 4; ++r) {
        const int M = brow + wr * 64 + m * 16 + lg * 4 + r;
        const float val = acc[m][n][r];
        if (z == 4) {
          outp[(size_t)M * DIM + o] = val + bias;
          continue;
        }
        const int b = M >> 10, s = M & (S - 1);
        const int bh = b * H + h;
        if (z == 0) {
          // 1/sqrt(Dh) folded in here (scores use pre-scaled q).
          const size_t idx2 = ((size_t)bh * S + s) * Dh + d;
          qu[idx2] = (__bf16)((val + bias + ubv) * SCALE);
          qv[idx2] = (__bf16)((val + bias + vbv) * SCALE);
        } else if (z == 1) {
          kk[((size_t)bh * S + s) * Dh + d] = (__bf16)(val + bias);
        } else if (z == 2) {
          // V^T with k-interleaved columns within each 32-block:
          // pos(t) = 2t (t<16) else 2t-31 -> matches attn's packed P stores.
          const int t = s & 31;
          const int sp = (s & ~31) | ((t < 16) ? (t << 1) : ((t << 1) - 31));
          vt[((size_t)bh * Dh + d) * S + sp] = (__bf16)(val + bias);
        } else {
          // phZ rows [S+1, 2S+1) = p; everything else pre-zeroed by memset.
          phZ[((size_t)bh * ZROWS + (S + 1 + s)) * Dh + d] = (__bf16)val;
        }
      }
    }
  }
}

// ---------------------------------------------------------------------------
// Kernel 2: fused attention. 256-thread blocks, 4 independent waves; each
// wave: 16 q-rows x full S. Grid 1024, XCD-resident (b,h). Max-free softmax.
// pos gather in registers via __shfl; uniform skip of zero pA/pB windows.
// ---------------------------------------------------------------------------
__global__ __launch_bounds__(256, 3) void attn_kernel(
    const __bf16* __restrict__ qu, const __bf16* __restrict__ qv,
    const __bf16* __restrict__ kk, const __bf16* __restrict__ vt,
    const __bf16* __restrict__ phZ,
    __bf16* __restrict__ ctx)
{
  __shared__ __align__(16) __bf16 at_all[4][2][16 * 40];

  const int tid = threadIdx.x;
  const int wid = tid >> 6;
  const int l = tid & 63;
  const int lm = l & 15, lg = l >> 4;

  const int bid = blockIdx.x;               // [0, 1024)
  const int j = bid >> 3;
  const int bh = (bid & 7) + 8 * (j & 7);   // all blocks of bh share an XCD
  const int q0 = (j >> 3) * 64 + wid * 16;
  const int h = bh & (H - 1), b = bh >> 4;

  const __bf16* qub = qu + (size_t)bh * S * Dh;
  const __bf16* qvb = qv + (size_t)bh * S * Dh;
  const __bf16* kb  = kk + (size_t)bh * S * Dh;
  const __bf16* vtb = vt + (size_t)bh * Dh * S;
  const __bf16* pZb = phZ + (size_t)bh * ZROWS * Dh;
  const __bf16* pAb = pZb + (size_t)(S + 1) * Dh;   // pA[m] = Z[S+1+m]

  const bf16x8 au  = *(const bf16x8*)(qub + (size_t)(q0 + lm) * Dh + lg * 8);
  const bf16x8 avA = *(const bf16x8*)(qvb + (size_t)(q0 + lm) * Dh + lg * 8);
  // row q+1 for the pB term; the one-past read is multiplied by zero pB rows.
  const bf16x8 avB = *(const bf16x8*)(qvb + (size_t)(q0 + 1 + lm) * Dh + lg * 8);

  // loop-invariant shuffle source lanes and tile-select predicates
  int  slr[4];
  bool prd[4];
#pragma unroll
  for (int r = 0; r < 4; ++r) {
    const int qr = lg * 4 + r;
    slr[r] = (l & 48) | ((lm - qr + 15) & 15);
    prd[r] = (lm <= qr);
  }

  float lrun[4] = {0.f, 0.f, 0.f, 0.f};
  f32x4 cta = {0.f,0.f,0.f,0.f}, ctb = {0.f,0.f,0.f,0.f};
  const f32x4 zero4 = {0.f,0.f,0.f,0.f};

  auto half_step = [&](int kt, __bf16* at) {
    // ---- content scores (q pre-scaled): [16 q x 32 k]
    bf16x8 kf0 = *(const bf16x8*)(kb + (size_t)(kt + lm) * Dh + lg * 8);
    bf16x8 kf1 = *(const bf16x8*)(kb + (size_t)(kt + 16 + lm) * Dh + lg * 8);
    f32x4 c0 = MFMA16(au, kf0, zero4);
    f32x4 c1 = MFMA16(au, kf1, zero4);

    // ---- positional scores over the 47-wide m window (3 tiles of 16)
    const int mlo = kt - q0 + (S - 16);
    f32x4 pt0 = zero4, pt1 = zero4, pt2 = zero4;
    if (mlo > S - 47) {          // pB window has nonzero rows
      pt0 = MFMA16(avB, *(const bf16x8*)(pZb + (size_t)(mlo + lm) * Dh + lg * 8), pt0);
      pt1 = MFMA16(avB, *(const bf16x8*)(pZb + (size_t)(mlo + 16 + lm) * Dh + lg * 8), pt1);
      pt2 = MFMA16(avB, *(const bf16x8*)(pZb + (size_t)(mlo + 32 + lm) * Dh + lg * 8), pt2);
    }
    if (mlo < S) {               // pA window has nonzero rows
      pt0 = MFMA16(avA, *(const bf16x8*)(pAb + (size_t)(mlo + lm) * Dh + lg * 8), pt0);
      pt1 = MFMA16(avA, *(const bf16x8*)(pAb + (size_t)(mlo + 16 + lm) * Dh + lg * 8), pt1);
      pt2 = MFMA16(avA, *(const bf16x8*)(pAb + (size_t)(mlo + 32 + lm) * Dh + lg * 8), pt2);
    }

    // ---- diagonal gather (register shuffles) + exp + packed P store
#pragma unroll
    for (int r = 0; r < 4; ++r) {
      const float v0 = __shfl(pt0[r], slr[r], 64);
      const float v1 = __shfl(pt1[r], slr[r], 64);
      const float v2 = __shfl(pt2[r], slr[r], 64);
      const float s0 = c0[r] + (prd[r] ? v0 : v1);
      const float s1 = c1[r] + (prd[r] ? v1 : v2);
      const float p0 = __expf(s0);
      const float p1 = __expf(s1);
      lrun[r] += p0 + p1;
      bf16x2 pp;
      pp[0] = (__bf16)p0;                    // k-col kt+lm     -> pos 2*lm
      pp[1] = (__bf16)p1;                    // k-col kt+16+lm  -> pos 2*lm+1
      *(bf16x2*)(at + (lg * 4 + r) * 40 + 2 * lm) = pp;
    }

    // ---- attn @ V (V^T columns are k-interleaved to match P positions)
    bf16x8 af  = *(const bf16x8*)(at + lm * 40 + lg * 8);
    bf16x8 vf0 = *(const bf16x8*)(vtb + (size_t)lm * S + kt + lg * 8);
    bf16x8 vf1 = *(const bf16x8*)(vtb + (size_t)(lm + 16) * S + kt + lg * 8);
    cta = MFMA16(af, vf0, cta);
    ctb = MFMA16(af, vf1, ctb);
  };

  __bf16* at0 = at_all[wid][0];
  __bf16* at1 = at_all[wid][1];
  for (int kt = 0; kt < S; kt += 64) {
    half_step(kt, at0);
    half_step(kt + 32, at1);
  }

  // ---- reduce row sums across 16-lane group; normalize + store ctx
#pragma unroll
  for (int r = 0; r < 4; ++r) {
    float rs = lrun[r];
    rs += __shfl_xor(rs, 1);
    rs += __shfl_xor(rs, 2);
    rs += __shfl_xor(rs, 4);
    rs += __shfl_xor(rs, 8);
    lrun[r] = rs;
  }

#pragma unroll
  for (int r = 0; r < 4; ++r) {
    const int s = q0 + lg * 4 + r;
    const float inv = 1.f / lrun[r];
    __bf16* cp = ctx + ((size_t)b * S + s) * DIM + h * Dh;
    cp[lm] = (__bf16)(cta[r] * inv);
    cp[16 + lm] = (__bf16)(ctb[r] * inv);
  }
}

// ---------------------------------------------------------------------------
extern "C" void kernel_launch(void* const* d_in, const int* in_sizes, int n_in,
                              void* d_out, int out_size, void* d_ws, size_t ws_size,
                              hipStream_t stream) {
  const float* query = (const float*)d_in[0];
  const float* key   = (const float*)d_in[1];
  const float* value = (const float*)d_in[2];
  const float* pos   = (const float*)d_in[3];
  const float* Wq = (const float*)d_in[4];
  const float* bq = (const float*)d_in[5];
  const float* Wk = (const float*)d_in[6];
  const float* bk = (const float*)d_in[7];
  const float* Wv = (const float*)d_in[8];
  const float* bv = (const float*)d_in[9];
  const float* Wp = (const float*)d_in[10];
  const float* ub = (const float*)d_in[11];
  const float* vb = (const float*)d_in[12];
  const float* Wo = (const float*)d_in[13];
  const float* bo = (const float*)d_in[14];
  float* out = (float*)d_out;

  char* ws = (char*)d_ws;
  const size_t MB = 1ull << 20;
  // Layout:
  //   [ 0,16) MB : xb (4x bf16 activations)
  //   [16,18.5)  : wb (5x bf16 weights)
  //   [19,23)    : qu   [23,27): qv   [27,31): kk   [31,35): vt
  //   [35,47.7)  : phZ [B*H, 3S+16, 32]
  //   [48,52)    : ctx bf16
  __bf16* xb  = (__bf16*)(ws + 0 * MB);
  __bf16* wb  = (__bf16*)(ws + 16 * MB);
  __bf16* qu  = (__bf16*)(ws + 19 * MB);
  __bf16* qv  = (__bf16*)(ws + 23 * MB);
  __bf16* kk  = (__bf16*)(ws + 27 * MB);
  __bf16* vt  = (__bf16*)(ws + 31 * MB);
  __bf16* phZ = (__bf16*)(ws + 35 * MB);
  __bf16* ctx = (__bf16*)(ws + 48 * MB);

  conv_kernel<<<dim3(1024, 9), dim3(256), 0, stream>>>(
      query, key, value, pos, Wq, Wk, Wv, Wp, Wo, xb, wb);

  hipMemsetAsync(phZ, 0, (size_t)64 * ZROWS * Dh * sizeof(__bf16), stream);

  gemm_kernel<<<dim3(512), dim3(256), 0, stream>>>(
      xb, wb, ctx, bq, bk, bv, bo, ub, vb,
      qu, qv, kk, vt, phZ, out, 0);

  attn_kernel<<<dim3(1024), dim3(256), 0, stream>>>(
      qu, qv, kk, vt, phZ, ctx);

  gemm_kernel<<<dim3(128), dim3(256), 0, stream>>>(
      xb, wb, ctx, bq, bk, bv, bo, ub, vb,
      qu, qv, kk, vt, phZ, out, 1);
}